// Round 3
// baseline (32.630 us; speedup 1.0000x reference)
//
#include <hip/hip_runtime.h>
#include <math.h>

#define NN 2048
#define RR 10
#define MM 2048
#define CC 84
#define GG 8            // n's per wave in match kernel
#define IEPS 1e-7f

// Kernel 1: one wave per (r, group-of-8-n). Each lane loads one m-box per
// 64-chunk (load amortized 8x vs per-(n,r) scan), computes corners once,
// tests all 8 wave-uniform pred boxes. Per-n ballot in m-order gives the
// first-match index (argmax-of-bool). Division-free compare:
// inter/(a1+a2-inter+eps) > 0.5  <=>  3*inter > a1+a2+eps.
__global__ __launch_bounds__(256) void match_kernel(
    const float* __restrict__ pred,
    const float* __restrict__ dpreds,
    int* __restrict__ first_idx) {
  const int NG = NN / GG;  // 256 groups
  int wid = (blockIdx.x * blockDim.x + threadIdx.x) >> 6;
  int lane = threadIdx.x & 63;
  if (wid >= NG * RR) return;
  int g = wid % NG;        // consecutive waves in a block share r -> L2 reuse
  int r = wid / NG;
  int nb = g * GG;

  // Wave-uniform per-n constants (registers; loop fully unrolled -> static idx)
  float bx1[GG], bx2[GG], by1[GG], by2[GG], a1e[GG];
#pragma unroll
  for (int i = 0; i < GG; ++i) {
    float4 pb = *reinterpret_cast<const float4*>(pred + (size_t)(nb + i) * CC);
    bx1[i] = fmaf(-0.5f, pb.z, pb.x);
    bx2[i] = fmaf(0.5f, pb.z, pb.x);
    by1[i] = fmaf(-0.5f, pb.w, pb.y);
    by2[i] = fmaf(0.5f, pb.w, pb.y);
    a1e[i] = pb.z * pb.w + IEPS;  // area1 + eps
  }

  const float4* __restrict__ dp =
      reinterpret_cast<const float4*>(dpreds + (size_t)r * MM * 4);

  unsigned done = 0;
  const unsigned ALL = (1u << GG) - 1;
  float4 d = dp[lane];  // chunk 0
  for (int m0 = 0; m0 < MM; m0 += 64) {
    float4 dn = d;
    if (m0 + 64 < MM) dn = dp[m0 + 64 + lane];  // prefetch next chunk early

    // Per-lane m-box derived values (computed once, reused for all 8 n)
    float x1 = fmaf(-0.5f, d.z, d.x), x2 = fmaf(0.5f, d.z, d.x);
    float y1 = fmaf(-0.5f, d.w, d.y), y2 = fmaf(0.5f, d.w, d.y);
    float a2 = d.z * d.w;

#pragma unroll
    for (int i = 0; i < GG; ++i) {
      if (done & (1u << i)) continue;  // wave-uniform branch (cheap)
      float iw = fmaxf(fminf(bx2[i], x2) - fmaxf(bx1[i], x1), 0.0f);
      float ih = fmaxf(fminf(by2[i], y2) - fmaxf(by1[i], y1), 0.0f);
      float inter = iw * ih;
      float t = a2 + a1e[i];
      unsigned long long bal = __ballot(3.0f * inter > t);
      if (bal) {
        done |= (1u << i);
        if (lane == 0)
          first_idx[(size_t)(nb + i) * RR + r] = m0 + (__ffsll(bal) - 1);
      }
    }
    if (done == ALL) break;
    d = dn;
  }
  if (lane == 0) {
#pragma unroll
    for (int i = 0; i < GG; ++i)
      if (!(done & (1u << i))) first_idx[(size_t)(nb + i) * RR + r] = -1;
  }
}

// Kernel 2: one wave per n. Lane l handles classes l and l+64 (C=84).
// entropy[c] = sum_r -p log p over matched r; softmax over c; out = 1 - min(sm).
__global__ __launch_bounds__(256) void entropy_kernel(
    const float* __restrict__ confs,
    const int* __restrict__ first_idx,
    float* __restrict__ out) {
  int lane = threadIdx.x & 63;
  int n = blockIdx.x * (blockDim.x >> 6) + (threadIdx.x >> 6);
  if (n >= NN) return;

  int idxs[RR];
  bool anym = false;
#pragma unroll
  for (int r = 0; r < RR; ++r) {
    idxs[r] = first_idx[n * RR + r];
    anym = anym || (idxs[r] >= 0);
  }

  const bool has_hi = (lane + 64) < CC;  // lanes 0..19 carry a 2nd class
  float e0 = 0.0f, e1 = 0.0f;
#pragma unroll
  for (int r = 0; r < RR; ++r) {
    if (idxs[r] >= 0) {
      const float* row = confs + ((size_t)r * MM + (size_t)idxs[r]) * CC;
      float p0 = row[lane];
      e0 -= p0 * __logf(p0);
      if (has_hi) {
        float p1 = row[lane + 64];
        e1 -= p1 * __logf(p1);
      }
    }
  }

  float maxE = fmaxf(e0, has_hi ? e1 : -INFINITY);
  float minE = fminf(e0, has_hi ? e1 : INFINITY);
#pragma unroll
  for (int off = 32; off >= 1; off >>= 1) {
    maxE = fmaxf(maxE, __shfl_xor(maxE, off));
    minE = fminf(minE, __shfl_xor(minE, off));
  }
  float s = __expf(e0 - maxE) + (has_hi ? __expf(e1 - maxE) : 0.0f);
#pragma unroll
  for (int off = 32; off >= 1; off >>= 1) s += __shfl_xor(s, off);

  float result = anym ? (1.0f - __expf(minE - maxE) / s) : nanf("");
  if (lane == 0) out[n] = result;
}

extern "C" void kernel_launch(void* const* d_in, const int* in_sizes, int n_in,
                              void* d_out, int out_size, void* d_ws, size_t ws_size,
                              hipStream_t stream) {
  const float* pred   = (const float*)d_in[0];   // (N, 84)
  const float* dpreds = (const float*)d_in[1];   // (R, M, 4)
  const float* confs  = (const float*)d_in[2];   // (R, M, 84)
  float* out = (float*)d_out;                    // (N,)
  int* first_idx = (int*)d_ws;                   // N*R ints

  // Kernel 1: R * N/GG waves = 2560, 4 waves/block -> 640 blocks
  {
    int total_waves = (NN / GG) * RR;
    int blocks = (total_waves * 64 + 255) / 256;
    match_kernel<<<blocks, 256, 0, stream>>>(pred, dpreds, first_idx);
  }
  // Kernel 2: one wave per n, 4 waves/block
  {
    int blocks = (NN + 3) / 4;                   // 512
    entropy_kernel<<<blocks, 256, 0, stream>>>(confs, first_idx, out);
  }
}

// Round 4
// 23.382 us; speedup vs baseline: 1.3955x; 1.3955x over previous
//
#include <hip/hip_runtime.h>
#include <math.h>

#define NN 2048
#define RR 10
#define MM 2048
#define CC 84
#define IEPS 1e-7f

// Kernel 1: one wave (64 lanes) per (r, n) pair; consecutive waves share r
// and have consecutive n -> same dpreds[r] stream over near-identical
// m-ranges (first hit ~ m==n) => L1/L2 line reuse across waves.
// Scan m in chunks of 256 (4 x 64 independent loads in flight), ballot on
// hit, first set bit in m-order = first match (argmax-of-bool semantics).
// Division-free: inter/(a1+a2-inter+eps) > 0.5  <=>  3*inter > a1+a2+eps.
__global__ __launch_bounds__(256) void match_kernel(
    const float* __restrict__ pred,
    const float* __restrict__ dpreds,
    int* __restrict__ first_idx) {
  int wid = (blockIdx.x * blockDim.x + threadIdx.x) >> 6;
  int lane = threadIdx.x & 63;
  if (wid >= NN * RR) return;
  int n = wid & (NN - 1);  // consecutive waves: consecutive n, same r
  int r = wid >> 11;       // NN = 2048 = 1<<11

  // pred row stride = 84 floats = 336 B (16B-aligned) -> float4 load OK
  float4 pb = *reinterpret_cast<const float4*>(pred + (size_t)n * CC);
  const float b1x1 = fmaf(-0.5f, pb.z, pb.x), b1x2 = fmaf(0.5f, pb.z, pb.x);
  const float b1y1 = fmaf(-0.5f, pb.w, pb.y), b1y2 = fmaf(0.5f, pb.w, pb.y);
  const float a1e = pb.z * pb.w + IEPS;  // area1 + eps

  const float4* __restrict__ dp =
      reinterpret_cast<const float4*>(dpreds + (size_t)r * MM * 4);

  int found = -1;
  for (int m0 = 0; m0 < MM; m0 += 256) {
    // 4 independent 16B loads in flight
    float4 d0 = dp[m0 + lane];
    float4 d1 = dp[m0 + 64 + lane];
    float4 d2 = dp[m0 + 128 + lane];
    float4 d3 = dp[m0 + 192 + lane];

#define HIT(db, h)                                                          \
    {                                                                       \
      float x1 = fmaf(-0.5f, db.z, db.x), x2 = fmaf(0.5f, db.z, db.x);      \
      float y1 = fmaf(-0.5f, db.w, db.y), y2 = fmaf(0.5f, db.w, db.y);      \
      float iw = fmaxf(fminf(b1x2, x2) - fmaxf(b1x1, x1), 0.0f);            \
      float ih = fmaxf(fminf(b1y2, y2) - fmaxf(b1y1, y1), 0.0f);            \
      float inter = iw * ih;                                                \
      float t = fmaf(db.z, db.w, a1e); /* a2 + a1 + eps */                  \
      h = (3.0f * inter > t);                                               \
    }
    bool h0, h1, h2, h3;
    HIT(d0, h0) HIT(d1, h1) HIT(d2, h2) HIT(d3, h3)
#undef HIT

    unsigned long long b0 = __ballot(h0);
    unsigned long long b1 = __ballot(h1);
    unsigned long long b2 = __ballot(h2);
    unsigned long long b3 = __ballot(h3);
    if (b0 | b1 | b2 | b3) {
      if (b0)      found = m0 +       (__ffsll(b0) - 1);
      else if (b1) found = m0 + 64  + (__ffsll(b1) - 1);
      else if (b2) found = m0 + 128 + (__ffsll(b2) - 1);
      else         found = m0 + 192 + (__ffsll(b3) - 1);
      break;
    }
  }
  if (lane == 0) first_idx[n * RR + r] = found;
}

// Kernel 2: one wave per n. Lane l handles classes l and l+64 (C=84).
// entropy[c] = sum_r -p log p over matched r; softmax over c; out = 1 - min(sm).
__global__ __launch_bounds__(256) void entropy_kernel(
    const float* __restrict__ confs,
    const int* __restrict__ first_idx,
    float* __restrict__ out) {
  int lane = threadIdx.x & 63;
  int n = blockIdx.x * (blockDim.x >> 6) + (threadIdx.x >> 6);
  if (n >= NN) return;

  int idxs[RR];
  bool anym = false;
#pragma unroll
  for (int r = 0; r < RR; ++r) {
    idxs[r] = first_idx[n * RR + r];
    anym = anym || (idxs[r] >= 0);
  }

  const bool has_hi = (lane + 64) < CC;  // lanes 0..19 carry a 2nd class
  float e0 = 0.0f, e1 = 0.0f;
#pragma unroll
  for (int r = 0; r < RR; ++r) {
    if (idxs[r] >= 0) {
      const float* row = confs + ((size_t)r * MM + (size_t)idxs[r]) * CC;
      float p0 = row[lane];
      e0 -= p0 * __logf(p0);
      if (has_hi) {
        float p1 = row[lane + 64];
        e1 -= p1 * __logf(p1);
      }
    }
  }

  float maxE = fmaxf(e0, has_hi ? e1 : -INFINITY);
  float minE = fminf(e0, has_hi ? e1 : INFINITY);
#pragma unroll
  for (int off = 32; off >= 1; off >>= 1) {
    maxE = fmaxf(maxE, __shfl_xor(maxE, off));
    minE = fminf(minE, __shfl_xor(minE, off));
  }
  float s = __expf(e0 - maxE) + (has_hi ? __expf(e1 - maxE) : 0.0f);
#pragma unroll
  for (int off = 32; off >= 1; off >>= 1) s += __shfl_xor(s, off);

  float result = anym ? (1.0f - __expf(minE - maxE) / s) : nanf("");
  if (lane == 0) out[n] = result;
}

extern "C" void kernel_launch(void* const* d_in, const int* in_sizes, int n_in,
                              void* d_out, int out_size, void* d_ws, size_t ws_size,
                              hipStream_t stream) {
  const float* pred   = (const float*)d_in[0];   // (N, 84)
  const float* dpreds = (const float*)d_in[1];   // (R, M, 4)
  const float* confs  = (const float*)d_in[2];   // (R, M, 84)
  float* out = (float*)d_out;                    // (N,)
  int* first_idx = (int*)d_ws;                   // N*R ints

  // Kernel 1: N*R waves, 4 waves/block (block = 4 consecutive n, same r)
  {
    int total_waves = NN * RR;                   // 20480
    int blocks = (total_waves * 64 + 255) / 256; // 5120
    match_kernel<<<blocks, 256, 0, stream>>>(pred, dpreds, first_idx);
  }
  // Kernel 2: one wave per n, 4 waves/block
  {
    int blocks = (NN + 3) / 4;                   // 512
    entropy_kernel<<<blocks, 256, 0, stream>>>(confs, first_idx, out);
  }
}